// Round 1
// baseline (772.500 us; speedup 1.0000x reference)
//
#include <hip/hip_runtime.h>

// ---------------------------------------------------------------------------
// 2-layer GCN forward:  out = A_norm * relu(A_norm * (x@W1) + b1) @ W2 + b2
// A_norm = D^-1/2 (A + I) D^-1/2, applied as dinv[dst] * sum dinv[src]*m[src]
// ---------------------------------------------------------------------------

// --- edge_index dtype detection (int32 vs int64 device layout) -------------
__global__ void detect_i64(const unsigned* ei, int E, int* flag) {
    __shared__ int nz;
    if (threadIdx.x == 0) nz = 0;
    __syncthreads();
    int samples = E < 2048 ? E : 2048;
    int cnt = 0;
    for (int i = threadIdx.x; i < samples; i += blockDim.x)
        if (ei[2 * i + 1] != 0u) cnt++;
    if (cnt) atomicAdd(&nz, cnt);
    __syncthreads();
    if (threadIdx.x == 0) *flag = (nz == 0) ? 1 : 0;  // all high-words zero -> int64
}

__global__ void init_deg(unsigned* deg, int n) {
    int i = blockIdx.x * blockDim.x + threadIdx.x;
    if (i < n) deg[i] = 1u;  // self-loop
}

__global__ void count_deg(const unsigned* ei, int E, const int* flag, unsigned* deg) {
    int e = blockIdx.x * blockDim.x + threadIdx.x;
    if (e >= E) return;
    int d = (*flag) ? (int)ei[2 * ((size_t)E + e)] : (int)ei[(size_t)E + e];
    atomicAdd(&deg[d], 1u);
}

__global__ void dinv_kernel(const unsigned* deg, float* dinv, int n) {
    int i = blockIdx.x * blockDim.x + threadIdx.x;
    if (i < n) dinv[i] = rsqrtf((float)deg[i]);
}

// --- exclusive scan of deg -> row_off (3 kernels) --------------------------
__global__ void scan_block_sums(const unsigned* deg, unsigned* partials, int n) {
    __shared__ unsigned sdata[256];
    int b = blockIdx.x, t = threadIdx.x;
    int base = b * 1024;
    unsigned s = 0;
    for (int j = 0; j < 4; j++) {
        int i = base + t * 4 + j;
        if (i < n) s += deg[i];
    }
    sdata[t] = s;
    __syncthreads();
    for (int stride = 128; stride > 0; stride >>= 1) {
        if (t < stride) sdata[t] += sdata[t + stride];
        __syncthreads();
    }
    if (t == 0) partials[b] = sdata[0];
}

__global__ void scan_partials(unsigned* partials, int nb) {
    if (threadIdx.x == 0 && blockIdx.x == 0) {
        unsigned run = 0;
        for (int i = 0; i < nb; i++) { unsigned v = partials[i]; partials[i] = run; run += v; }
    }
}

__global__ void scan_write(const unsigned* deg, const unsigned* partials,
                           int* row_off, int* cursor, int n) {
    int b = blockIdx.x, t = threadIdx.x;
    int lane = t & 63, wid = t >> 6;
    int base = b * 1024;
    unsigned vals[4];
    unsigned s = 0;
    for (int j = 0; j < 4; j++) {
        int i = base + t * 4 + j;
        vals[j] = (i < n) ? deg[i] : 0u;
        s += vals[j];
    }
    unsigned inc = s;
    for (int o = 1; o < 64; o <<= 1) {
        unsigned u = (unsigned)__shfl_up((int)inc, o, 64);
        if (lane >= o) inc += u;
    }
    __shared__ unsigned wtot[4];
    if (lane == 63) wtot[wid] = inc;
    __syncthreads();
    unsigned wbase = 0;
    for (int w = 0; w < wid; w++) wbase += wtot[w];
    unsigned excl = partials[b] + wbase + (inc - s);
    for (int j = 0; j < 4; j++) {
        int i = base + t * 4 + j;
        if (i < n) { row_off[i] = (int)excl; cursor[i] = (int)excl; excl += vals[j]; }
    }
}

__global__ void scatter_edges(const unsigned* ei, int E, int n, const int* flag,
                              int* cursor, int* csr_src) {
    int e = blockIdx.x * blockDim.x + threadIdx.x;
    int total = E + n;
    if (e >= total) return;
    int s, d;
    if (e < E) {
        if (*flag) { s = (int)ei[2 * (size_t)e]; d = (int)ei[2 * ((size_t)E + e)]; }
        else       { s = (int)ei[e];             d = (int)ei[(size_t)E + e]; }
    } else {
        s = d = e - E;
    }
    int pos = atomicAdd(&cursor[d], 1);
    csr_src[pos] = s;
}

// --- fp32 GEMM: C[M,128] = A[M,128] @ W[128,128] ---------------------------
__global__ __launch_bounds__(256) void gemm_nn_128(const float* __restrict__ A,
                                                   const float* __restrict__ W,
                                                   float* __restrict__ C, int M) {
    __shared__ float As[128 * 129];   // stride 129: conflict-free a-column reads
    __shared__ float Ws[128 * 128];
    const int t = threadIdx.x;
    const int row0 = blockIdx.x * 128;
    {
        const float4* W4 = (const float4*)W;
        float4* Ws4 = (float4*)Ws;
        for (int i = t; i < 128 * 32; i += 256) Ws4[i] = W4[i];
        const float4* A4 = (const float4*)A;
        for (int i = t; i < 128 * 32; i += 256) {
            int r = i >> 5, c4 = i & 31;
            int gr = row0 + r;
            float4 v = make_float4(0.f, 0.f, 0.f, 0.f);
            if (gr < M) v = A4[(size_t)gr * 32 + c4];
            float* dst = &As[r * 129 + c4 * 4];
            dst[0] = v.x; dst[1] = v.y; dst[2] = v.z; dst[3] = v.w;
        }
    }
    __syncthreads();
    const int tx = t & 15, ty = t >> 4;
    float acc[8][8];
#pragma unroll
    for (int i = 0; i < 8; i++)
#pragma unroll
        for (int j = 0; j < 8; j++) acc[i][j] = 0.f;
    const float* Ab = &As[(ty * 8) * 129];
#pragma unroll 2
    for (int k = 0; k < 128; k++) {
        float a[8];
#pragma unroll
        for (int i = 0; i < 8; i++) a[i] = Ab[i * 129 + k];
        const float4* wr = (const float4*)&Ws[k * 128 + tx * 8];
        float4 b0 = wr[0], b1 = wr[1];
        float bb[8] = {b0.x, b0.y, b0.z, b0.w, b1.x, b1.y, b1.z, b1.w};
#pragma unroll
        for (int i = 0; i < 8; i++)
#pragma unroll
            for (int j = 0; j < 8; j++) acc[i][j] = fmaf(a[i], bb[j], acc[i][j]);
    }
#pragma unroll
    for (int i = 0; i < 8; i++) {
        int gr = row0 + ty * 8 + i;
        if (gr < M) {
            float4* Cr = (float4*)&C[(size_t)gr * 128 + tx * 8];
            Cr[0] = make_float4(acc[i][0], acc[i][1], acc[i][2], acc[i][3]);
            Cr[1] = make_float4(acc[i][4], acc[i][5], acc[i][6], acc[i][7]);
        }
    }
}

// --- aggregation: out[v] = dinv[v] * sum_{e in CSR(v)} dinv[src]*m[src] + b
__global__ void agg_kernel(const float* __restrict__ m, const int* __restrict__ csr,
                           const int* __restrict__ row_off, const unsigned* __restrict__ deg,
                           const float* __restrict__ dinv, const float* __restrict__ bias,
                           float* __restrict__ out, int n, int do_relu) {
    int wid = threadIdx.x >> 6, lane = threadIdx.x & 63;
    int v = blockIdx.x * 4 + wid;
    if (v >= n) return;
    int start = row_off[v];
    int cnt = (int)deg[v];
    const float2* m2 = (const float2*)m;
    float ax = 0.f, ay = 0.f;
    for (int e = 0; e < cnt; e++) {
        int s = csr[start + e];
        float w = dinv[s];
        float2 val = m2[(size_t)s * 64 + lane];
        ax = fmaf(w, val.x, ax);
        ay = fmaf(w, val.y, ay);
    }
    float dv = dinv[v];
    float2 b = ((const float2*)bias)[lane];
    float ox = fmaf(dv, ax, b.x), oy = fmaf(dv, ay, b.y);
    if (do_relu) { ox = fmaxf(ox, 0.f); oy = fmaxf(oy, 0.f); }
    ((float2*)out)[(size_t)v * 64 + lane] = make_float2(ox, oy);
}

extern "C" void kernel_launch(void* const* d_in, const int* in_sizes, int n_in,
                              void* d_out, int out_size, void* d_ws, size_t ws_size,
                              hipStream_t stream) {
    const float*    x  = (const float*)d_in[0];
    const float*    W1 = (const float*)d_in[1];
    const float*    b1 = (const float*)d_in[2];
    const float*    W2 = (const float*)d_in[3];
    const float*    b2 = (const float*)d_in[4];
    const unsigned* ei = (const unsigned*)d_in[5];
    int n = in_sizes[0] / 128;
    int E = in_sizes[5] / 2;
    float* out = (float*)d_out;

    char* w = (char*)d_ws;
    size_t off = 0;
    auto alloc = [&](size_t bytes) -> void* {
        void* p = w + off;
        off = (off + bytes + 255) & ~(size_t)255;
        return p;
    };
    int*      flag     = (int*)alloc(4);
    unsigned* deg      = (unsigned*)alloc((size_t)n * 4);
    float*    dinv     = (float*)alloc((size_t)n * 4);
    int*      row_off  = (int*)alloc((size_t)n * 4);
    int*      cursor   = (int*)alloc((size_t)n * 4);
    unsigned* partials = (unsigned*)alloc(4096 * 4);
    int*      csr      = (int*)alloc((size_t)(E + n) * 4);
    float*    m        = (float*)alloc((size_t)n * 128 * 4);
    (void)ws_size; (void)n_in; (void)out_size;

    int nb = (n + 1023) / 1024;

    hipLaunchKernelGGL(detect_i64, dim3(1), dim3(256), 0, stream, ei, E, flag);
    hipLaunchKernelGGL(init_deg, dim3((n + 255) / 256), dim3(256), 0, stream, deg, n);
    hipLaunchKernelGGL(count_deg, dim3((E + 255) / 256), dim3(256), 0, stream, ei, E, flag, deg);
    hipLaunchKernelGGL(dinv_kernel, dim3((n + 255) / 256), dim3(256), 0, stream, deg, dinv, n);
    hipLaunchKernelGGL(scan_block_sums, dim3(nb), dim3(256), 0, stream, deg, partials, n);
    hipLaunchKernelGGL(scan_partials, dim3(1), dim3(64), 0, stream, partials, nb);
    hipLaunchKernelGGL(scan_write, dim3(nb), dim3(256), 0, stream, deg, partials, row_off, cursor, n);
    hipLaunchKernelGGL(scatter_edges, dim3((E + n + 255) / 256), dim3(256), 0, stream,
                       ei, E, n, flag, cursor, csr);

    // layer 1: m = x@W1 ; h(=out) = relu(agg(m) + b1)
    hipLaunchKernelGGL(gemm_nn_128, dim3((n + 127) / 128), dim3(256), 0, stream, x, W1, m, n);
    hipLaunchKernelGGL(agg_kernel, dim3((n + 3) / 4), dim3(256), 0, stream,
                       m, csr, row_off, deg, dinv, b1, out, n, 1);
    // layer 2: m = h@W2 ; out = agg(m) + b2
    hipLaunchKernelGGL(gemm_nn_128, dim3((n + 127) / 128), dim3(256), 0, stream, out, W2, m, n);
    hipLaunchKernelGGL(agg_kernel, dim3((n + 3) / 4), dim3(256), 0, stream,
                       m, csr, row_off, deg, dinv, b2, out, n, 0);
}

// Round 2
// 490.309 us; speedup vs baseline: 1.5755x; 1.5755x over previous
//
#include <hip/hip_runtime.h>

// ---------------------------------------------------------------------------
// 2-layer GCN forward:  out = A_norm * relu(A_norm * (x@W1) + b1) @ W2 + b2
// A_norm = D^-1/2 (A+I) D^-1/2, applied as dinv[dst] * sum( dinv[src]*m[src] )
// m stored bf16 with dinv[src] pre-folded (halves gather traffic).
// ---------------------------------------------------------------------------

__device__ inline float bf_lo(unsigned w) { return __uint_as_float(w << 16); }
__device__ inline float bf_hi(unsigned w) { return __uint_as_float(w & 0xffff0000u); }
__device__ inline unsigned bf16pair(float lo, float hi) {  // RNE pack
    unsigned a = __float_as_uint(lo), b = __float_as_uint(hi);
    a += 0x7fffu + ((a >> 16) & 1u);
    b += 0x7fffu + ((b >> 16) & 1u);
    return (a >> 16) | (b & 0xffff0000u);
}

// --- edge_index dtype detection (int32 vs int64 device layout) -------------
__global__ void detect_i64(const unsigned* ei, int E, int* flag) {
    __shared__ int nz;
    if (threadIdx.x == 0) nz = 0;
    __syncthreads();
    int samples = E < 2048 ? E : 2048;
    int cnt = 0;
    for (int i = threadIdx.x; i < samples; i += blockDim.x)
        if (ei[2 * i + 1] != 0u) cnt++;
    if (cnt) atomicAdd(&nz, cnt);
    __syncthreads();
    if (threadIdx.x == 0) *flag = (nz == 0) ? 1 : 0;  // all high words zero -> int64
}

__global__ void init_deg(unsigned* deg, int n) {
    int i = blockIdx.x * blockDim.x + threadIdx.x;
    if (i < n) deg[i] = 1u;  // self-loop
}

__global__ void count_deg(const unsigned* ei, int E, const int* flag, unsigned* deg) {
    int e = blockIdx.x * blockDim.x + threadIdx.x;
    if (e >= E) return;
    int d = (*flag) ? (int)ei[2 * ((size_t)E + e)] : (int)ei[(size_t)E + e];
    atomicAdd(&deg[d], 1u);
}

__global__ void dinv_kernel(const unsigned* deg, float* dinv, int n) {
    int i = blockIdx.x * blockDim.x + threadIdx.x;
    if (i < n) dinv[i] = rsqrtf((float)deg[i]);
}

// --- exclusive scan of deg -> row_off --------------------------------------
__global__ void scan_block_sums(const unsigned* deg, unsigned* partials, int n) {
    __shared__ unsigned sdata[256];
    int b = blockIdx.x, t = threadIdx.x;
    int base = b * 1024;
    unsigned s = 0;
    for (int j = 0; j < 4; j++) {
        int i = base + t * 4 + j;
        if (i < n) s += deg[i];
    }
    sdata[t] = s;
    __syncthreads();
    for (int stride = 128; stride > 0; stride >>= 1) {
        if (t < stride) sdata[t] += sdata[t + stride];
        __syncthreads();
    }
    if (t == 0) partials[b] = sdata[0];
}

__global__ void scan_partials(unsigned* partials, int nb) {
    if (threadIdx.x == 0 && blockIdx.x == 0) {
        unsigned run = 0;
        for (int i = 0; i < nb; i++) { unsigned v = partials[i]; partials[i] = run; run += v; }
    }
}

__global__ void scan_write(const unsigned* deg, const unsigned* partials,
                           int* row_off, int* cursor, int n) {
    int b = blockIdx.x, t = threadIdx.x;
    int lane = t & 63, wid = t >> 6;
    int base = b * 1024;
    unsigned vals[4];
    unsigned s = 0;
    for (int j = 0; j < 4; j++) {
        int i = base + t * 4 + j;
        vals[j] = (i < n) ? deg[i] : 0u;
        s += vals[j];
    }
    unsigned inc = s;
    for (int o = 1; o < 64; o <<= 1) {
        unsigned u = (unsigned)__shfl_up((int)inc, o, 64);
        if (lane >= o) inc += u;
    }
    __shared__ unsigned wtot[4];
    if (lane == 63) wtot[wid] = inc;
    __syncthreads();
    unsigned wbase = 0;
    for (int w = 0; w < wid; w++) wbase += wtot[w];
    unsigned excl = partials[b] + wbase + (inc - s);
    for (int j = 0; j < 4; j++) {
        int i = base + t * 4 + j;
        if (i < n) { row_off[i] = (int)excl; cursor[i] = (int)excl; excl += vals[j]; }
    }
}

__global__ void scatter_edges(const unsigned* ei, int E, int n, const int* flag,
                              int* cursor, int* csr_src) {
    int e = blockIdx.x * blockDim.x + threadIdx.x;
    int total = E + n;
    if (e >= total) return;
    int s, d;
    if (e < E) {
        if (*flag) { s = (int)ei[2 * (size_t)e]; d = (int)ei[2 * ((size_t)E + e)]; }
        else       { s = (int)ei[e];             d = (int)ei[(size_t)E + e]; }
    } else {
        s = d = e - E;
    }
    int pos = atomicAdd(&cursor[d], 1);
    csr_src[pos] = s;
}

// --- GEMM: Mout[M,128](bf16) = dinv[r] * (A[M,128] @ W[128,128]) ------------
// A fp32 or bf16 (a_bf16 flag). W read from global (L1/L2-resident, 64 KB).
__global__ __launch_bounds__(128) void gemm_128(const void* __restrict__ Ain, int a_bf16,
                                                const float* __restrict__ W,
                                                const float* __restrict__ dinv,
                                                unsigned short* __restrict__ Mout, int M) {
    __shared__ float As[64 * 129];  // stride 129: conflict-free column reads
    const int t = threadIdx.x;
    const int row0 = blockIdx.x * 64;
    if (a_bf16) {
        const uint4* A4 = (const uint4*)Ain;  // 8 bf16 per uint4
        for (int i = t; i < 64 * 16; i += 128) {
            int r = i >> 4, c8 = i & 15;
            int gr = row0 + r;
            uint4 v = make_uint4(0u, 0u, 0u, 0u);
            if (gr < M) v = A4[(size_t)gr * 16 + c8];
            float* dst = &As[r * 129 + c8 * 8];
            unsigned u[4] = {v.x, v.y, v.z, v.w};
#pragma unroll
            for (int q = 0; q < 4; q++) {
                dst[2 * q]     = bf_lo(u[q]);
                dst[2 * q + 1] = bf_hi(u[q]);
            }
        }
    } else {
        const float4* A4 = (const float4*)Ain;
        for (int i = t; i < 64 * 32; i += 128) {
            int r = i >> 5, c4 = i & 31;
            int gr = row0 + r;
            float4 v = make_float4(0.f, 0.f, 0.f, 0.f);
            if (gr < M) v = A4[(size_t)gr * 32 + c4];
            float* dst = &As[r * 129 + c4 * 4];
            dst[0] = v.x; dst[1] = v.y; dst[2] = v.z; dst[3] = v.w;
        }
    }
    __syncthreads();
    const int tx = t & 15, ty = t >> 4;  // 16 x 8 thread grid, 8x8 tile each
    float acc[8][8];
#pragma unroll
    for (int i = 0; i < 8; i++)
#pragma unroll
        for (int j = 0; j < 8; j++) acc[i][j] = 0.f;
    const float* Ab = &As[(ty * 8) * 129];
    const float4* W4 = (const float4*)W;
#pragma unroll 2
    for (int k = 0; k < 128; k++) {
        float a[8];
#pragma unroll
        for (int i = 0; i < 8; i++) a[i] = Ab[i * 129 + k];
        float4 b0 = W4[k * 32 + tx * 2];
        float4 b1 = W4[k * 32 + tx * 2 + 1];
        float bb[8] = {b0.x, b0.y, b0.z, b0.w, b1.x, b1.y, b1.z, b1.w};
#pragma unroll
        for (int i = 0; i < 8; i++)
#pragma unroll
            for (int j = 0; j < 8; j++) acc[i][j] = fmaf(a[i], bb[j], acc[i][j]);
    }
#pragma unroll
    for (int i = 0; i < 8; i++) {
        int gr = row0 + ty * 8 + i;
        if (gr < M) {
            float dv = dinv[gr];
            unsigned p0 = bf16pair(acc[i][0] * dv, acc[i][1] * dv);
            unsigned p1 = bf16pair(acc[i][2] * dv, acc[i][3] * dv);
            unsigned p2 = bf16pair(acc[i][4] * dv, acc[i][5] * dv);
            unsigned p3 = bf16pair(acc[i][6] * dv, acc[i][7] * dv);
            *(uint4*)(Mout + (size_t)gr * 128 + tx * 8) = make_uint4(p0, p1, p2, p3);
        }
    }
}

// --- aggregation: out[v] = dinv[v]*sum_{e} m'[src_e] + b  (m' bf16, 256B/row)
__global__ __launch_bounds__(256) void agg_kernel(const unsigned* __restrict__ m,
                                                  const int* __restrict__ csr,
                                                  const int* __restrict__ row_off,
                                                  const unsigned* __restrict__ deg,
                                                  const float* __restrict__ dinv,
                                                  const float* __restrict__ bias,
                                                  void* __restrict__ outp, int n, int mode) {
    int wid = threadIdx.x >> 6, lane = threadIdx.x & 63;
    int v = blockIdx.x * 4 + wid;
    if (v >= n) return;
    int start = row_off[v];
    int cnt = (int)deg[v];
    float ax = 0.f, ay = 0.f;
    int e = 0;
    while (e < cnt) {
        int nload = cnt - e;
        if (nload > 64) nload = 64;
        int sv = 0;
        if (lane < nload) sv = csr[start + e + lane];
        int nfull = nload & ~7;
        int j = 0;
        for (; j < nfull; j += 8) {
            int s0 = __shfl(sv, j + 0), s1 = __shfl(sv, j + 1);
            int s2 = __shfl(sv, j + 2), s3 = __shfl(sv, j + 3);
            int s4 = __shfl(sv, j + 4), s5 = __shfl(sv, j + 5);
            int s6 = __shfl(sv, j + 6), s7 = __shfl(sv, j + 7);
            unsigned w0 = m[(size_t)s0 * 64 + lane];
            unsigned w1 = m[(size_t)s1 * 64 + lane];
            unsigned w2 = m[(size_t)s2 * 64 + lane];
            unsigned w3 = m[(size_t)s3 * 64 + lane];
            unsigned w4 = m[(size_t)s4 * 64 + lane];
            unsigned w5 = m[(size_t)s5 * 64 + lane];
            unsigned w6 = m[(size_t)s6 * 64 + lane];
            unsigned w7 = m[(size_t)s7 * 64 + lane];
            ax += bf_lo(w0); ay += bf_hi(w0);
            ax += bf_lo(w1); ay += bf_hi(w1);
            ax += bf_lo(w2); ay += bf_hi(w2);
            ax += bf_lo(w3); ay += bf_hi(w3);
            ax += bf_lo(w4); ay += bf_hi(w4);
            ax += bf_lo(w5); ay += bf_hi(w5);
            ax += bf_lo(w6); ay += bf_hi(w6);
            ax += bf_lo(w7); ay += bf_hi(w7);
        }
        for (; j < nload; j++) {
            int s = __shfl(sv, j);
            unsigned w = m[(size_t)s * 64 + lane];
            ax += bf_lo(w); ay += bf_hi(w);
        }
        e += nload;
    }
    float dv = dinv[v];
    float2 b = ((const float2*)bias)[lane];
    float ox = fmaf(dv, ax, b.x), oy = fmaf(dv, ay, b.y);
    if (mode) {  // relu + bf16 (hidden layer)
        ox = fmaxf(ox, 0.f); oy = fmaxf(oy, 0.f);
        ((unsigned*)outp)[(size_t)v * 64 + lane] = bf16pair(ox, oy);
    } else {     // final fp32 output
        ((float2*)outp)[(size_t)v * 64 + lane] = make_float2(ox, oy);
    }
}

extern "C" void kernel_launch(void* const* d_in, const int* in_sizes, int n_in,
                              void* d_out, int out_size, void* d_ws, size_t ws_size,
                              hipStream_t stream) {
    const float*    x  = (const float*)d_in[0];
    const float*    W1 = (const float*)d_in[1];
    const float*    b1 = (const float*)d_in[2];
    const float*    W2 = (const float*)d_in[3];
    const float*    b2 = (const float*)d_in[4];
    const unsigned* ei = (const unsigned*)d_in[5];
    int n = in_sizes[0] / 128;
    int E = in_sizes[5] / 2;
    float* out = (float*)d_out;

    char* w = (char*)d_ws;
    size_t off = 0;
    auto alloc = [&](size_t bytes) -> void* {
        void* p = w + off;
        off = (off + bytes + 255) & ~(size_t)255;
        return p;
    };
    int*            flag     = (int*)alloc(4);
    unsigned*       deg      = (unsigned*)alloc((size_t)n * 4);
    float*          dinv     = (float*)alloc((size_t)n * 4);
    int*            row_off  = (int*)alloc((size_t)n * 4);
    int*            cursor   = (int*)alloc((size_t)n * 4);
    unsigned*       partials = (unsigned*)alloc(4096 * 4);
    int*            csr      = (int*)alloc((size_t)(E + n) * 4);
    unsigned short* m_bf     = (unsigned short*)alloc((size_t)n * 128 * 2);
    unsigned*       h_bf     = (unsigned*)alloc((size_t)n * 64 * 4);
    (void)ws_size; (void)n_in; (void)out_size;

    int nb = (n + 1023) / 1024;

    hipLaunchKernelGGL(detect_i64, dim3(1), dim3(256), 0, stream, ei, E, flag);
    hipLaunchKernelGGL(init_deg, dim3((n + 255) / 256), dim3(256), 0, stream, deg, n);
    hipLaunchKernelGGL(count_deg, dim3((E + 255) / 256), dim3(256), 0, stream, ei, E, flag, deg);
    hipLaunchKernelGGL(dinv_kernel, dim3((n + 255) / 256), dim3(256), 0, stream, deg, dinv, n);
    hipLaunchKernelGGL(scan_block_sums, dim3(nb), dim3(256), 0, stream, deg, partials, n);
    hipLaunchKernelGGL(scan_partials, dim3(1), dim3(64), 0, stream, partials, nb);
    hipLaunchKernelGGL(scan_write, dim3(nb), dim3(256), 0, stream, deg, partials, row_off, cursor, n);
    hipLaunchKernelGGL(scatter_edges, dim3((E + n + 255) / 256), dim3(256), 0, stream,
                       ei, E, n, flag, cursor, csr);

    // layer 1: m = dinv*(x@W1) ; h = bf16(relu(agg(m) + b1))
    hipLaunchKernelGGL(gemm_128, dim3((n + 63) / 64), dim3(128), 0, stream,
                       (const void*)x, 0, W1, dinv, m_bf, n);
    hipLaunchKernelGGL(agg_kernel, dim3((n + 3) / 4), dim3(256), 0, stream,
                       (const unsigned*)m_bf, csr, row_off, deg, dinv, b1, (void*)h_bf, n, 1);
    // layer 2: m = dinv*(h@W2) ; out = agg(m) + b2
    hipLaunchKernelGGL(gemm_128, dim3((n + 63) / 64), dim3(128), 0, stream,
                       (const void*)h_bf, 1, W2, dinv, m_bf, n);
    hipLaunchKernelGGL(agg_kernel, dim3((n + 3) / 4), dim3(256), 0, stream,
                       (const unsigned*)m_bf, csr, row_off, deg, dinv, b2, (void*)out, n, 0);
}

// Round 3
// 345.424 us; speedup vs baseline: 2.2364x; 1.4194x over previous
//
#include <hip/hip_runtime.h>

// ---------------------------------------------------------------------------
// 2-layer GCN forward:  out = A_norm * relu(A_norm * (x@W1) + b1) @ W2 + b2
// A_norm = D^-1/2 (A+I) D^-1/2, applied as dinv[dst] * sum( dinv[src]*m[src] )
// m stored bf16 with dinv[src] pre-folded. CSR built via 512-node buckets to
// avoid random-4B-store write amplification (108MB -> ~7MB).
// ---------------------------------------------------------------------------

#define RB    9
#define RANGE 512
#define CAPB  16384   // records per bucket (avg ~8163 at E=1.6M, NB=196)
#define CHUNK 8192    // edges per bucketA block

__device__ inline float bf_lo(unsigned w) { return __uint_as_float(w << 16); }
__device__ inline float bf_hi(unsigned w) { return __uint_as_float(w & 0xffff0000u); }
__device__ inline unsigned bf16pair(float lo, float hi) {  // RNE pack
    unsigned a = __float_as_uint(lo), b = __float_as_uint(hi);
    a += 0x7fffu + ((a >> 16) & 1u);
    b += 0x7fffu + ((b >> 16) & 1u);
    return (a >> 16) | (b & 0xffff0000u);
}

// --- edge_index dtype detection (int32 vs int64 device layout) -------------
__global__ void detect_i64(const unsigned* ei, int E, int* flag) {
    __shared__ int nz;
    if (threadIdx.x == 0) nz = 0;
    __syncthreads();
    int samples = E < 2048 ? E : 2048;
    int cnt = 0;
    for (int i = threadIdx.x; i < samples; i += blockDim.x)
        if (ei[2 * i + 1] != 0u) cnt++;
    if (cnt) atomicAdd(&nz, cnt);
    __syncthreads();
    if (threadIdx.x == 0) *flag = (nz == 0) ? 1 : 0;  // all high words zero -> int64
}

__global__ void init_gcur(unsigned* gcur, int NB) {
    int b = blockIdx.x * blockDim.x + threadIdx.x;
    if (b < NB) gcur[b] = (unsigned)b * CAPB;
}

// --- phase A: edges -> per-bucket record arrays (4B records) ---------------
__global__ __launch_bounds__(256) void bucketA(const unsigned* __restrict__ ei, int E, int n,
                                               const int* __restrict__ flag,
                                               unsigned* __restrict__ gcur,
                                               unsigned* __restrict__ recs) {
    __shared__ unsigned hist[512];
    __shared__ unsigned offs[512];
    const int t = threadIdx.x;
    const int NB = (n + RANGE - 1) >> RB;
    for (int i = t; i < NB; i += 256) hist[i] = 0u;
    __syncthreads();
    const int base = blockIdx.x * CHUNK;
    const bool i64 = (*flag != 0);
    unsigned rec[32], bk[32];
#pragma unroll
    for (int j = 0; j < 32; j++) {
        int i = base + j * 256 + t;
        unsigned bv = 0xffffffffu, rv = 0u;
        if (i < E) {
            unsigned s, d;
            if (i64) { s = ei[2 * (size_t)i]; d = ei[2 * ((size_t)E + i)]; }
            else     { s = ei[i];             d = ei[(size_t)E + i]; }
            bv = d >> RB;
            rv = (s << RB) | (d & (RANGE - 1));
            atomicAdd(&hist[bv], 1u);
        }
        rec[j] = rv; bk[j] = bv;
    }
    __syncthreads();
    for (int b = t; b < NB; b += 256) {
        unsigned h = hist[b];
        offs[b] = h ? atomicAdd(&gcur[b], h) : 0u;
    }
    __syncthreads();
#pragma unroll
    for (int j = 0; j < 32; j++) {
        unsigned b = bk[j];
        if (b != 0xffffffffu) {
            unsigned pos = atomicAdd(&offs[b], 1u);
            if (pos < (b + 1u) * CAPB) recs[pos] = rec[j];  // clamp (memory safety)
        }
    }
}

// --- phase A2: per-bucket degree count (self-loop included) ----------------
__global__ __launch_bounds__(256) void bucket_deg(const unsigned* __restrict__ gcur,
                                                  const unsigned* __restrict__ recs,
                                                  unsigned* __restrict__ deg, int n) {
    __shared__ unsigned dl[RANGE];
    const int b = blockIdx.x, t = threadIdx.x;
    const int node0 = b << RB;
    for (int v = t; v < RANGE; v += 256) dl[v] = 1u;  // self-loop
    __syncthreads();
    unsigned base = (unsigned)b * CAPB;
    unsigned cnt = gcur[b] - base; if (cnt > CAPB) cnt = CAPB;
    for (unsigned i = t; i < cnt; i += 256)
        atomicAdd(&dl[recs[base + i] & (RANGE - 1)], 1u);
    __syncthreads();
    for (int v = t; v < RANGE; v += 256)
        if (node0 + v < n) deg[node0 + v] = dl[v];
}

__global__ void dinv_kernel(const unsigned* deg, float* dinv, int n) {
    int i = blockIdx.x * blockDim.x + threadIdx.x;
    if (i < n) dinv[i] = rsqrtf((float)deg[i]);
}

// --- exclusive scan of deg -> row_off --------------------------------------
__global__ void scan_block_sums(const unsigned* deg, unsigned* partials, int n) {
    __shared__ unsigned sdata[256];
    int b = blockIdx.x, t = threadIdx.x;
    int base = b * 1024;
    unsigned s = 0;
    for (int j = 0; j < 4; j++) {
        int i = base + t * 4 + j;
        if (i < n) s += deg[i];
    }
    sdata[t] = s;
    __syncthreads();
    for (int stride = 128; stride > 0; stride >>= 1) {
        if (t < stride) sdata[t] += sdata[t + stride];
        __syncthreads();
    }
    if (t == 0) partials[b] = sdata[0];
}

__global__ void scan_partials(unsigned* partials, int nb) {
    if (threadIdx.x == 0 && blockIdx.x == 0) {
        unsigned run = 0;
        for (int i = 0; i < nb; i++) { unsigned v = partials[i]; partials[i] = run; run += v; }
    }
}

__global__ void scan_write(const unsigned* deg, const unsigned* partials,
                           int* row_off, int n) {
    int b = blockIdx.x, t = threadIdx.x;
    int lane = t & 63, wid = t >> 6;
    int base = b * 1024;
    unsigned vals[4];
    unsigned s = 0;
    for (int j = 0; j < 4; j++) {
        int i = base + t * 4 + j;
        vals[j] = (i < n) ? deg[i] : 0u;
        s += vals[j];
    }
    unsigned inc = s;
    for (int o = 1; o < 64; o <<= 1) {
        unsigned u = (unsigned)__shfl_up((int)inc, o, 64);
        if (lane >= o) inc += u;
    }
    __shared__ unsigned wtot[4];
    if (lane == 63) wtot[wid] = inc;
    __syncthreads();
    unsigned wbase = 0;
    for (int w = 0; w < wid; w++) wbase += wtot[w];
    unsigned excl = partials[b] + wbase + (inc - s);
    for (int j = 0; j < 4; j++) {
        int i = base + t * 4 + j;
        if (i < n) { row_off[i] = (int)excl; excl += vals[j]; }
    }
}

// --- phase B: per-bucket CSR scatter (L2-resident ~35KB windows) -----------
__global__ __launch_bounds__(256) void bucket_csr(const unsigned* __restrict__ gcur,
                                                  const unsigned* __restrict__ recs,
                                                  const int* __restrict__ row_off,
                                                  int* __restrict__ csr, int n) {
    __shared__ int cur[RANGE];
    const int b = blockIdx.x, t = threadIdx.x;
    const int node0 = b << RB;
    for (int v = t; v < RANGE; v += 256) {
        int node = node0 + v;
        if (node < n) {
            int ro = row_off[node];
            csr[ro] = node;      // self-loop entry
            cur[v] = ro + 1;
        }
    }
    __syncthreads();
    unsigned base = (unsigned)b * CAPB;
    unsigned cnt = gcur[b] - base; if (cnt > CAPB) cnt = CAPB;
    for (unsigned i = t; i < cnt; i += 256) {
        unsigned r = recs[base + i];
        int pos = atomicAdd(&cur[r & (RANGE - 1)], 1);
        csr[pos] = (int)(r >> RB);
    }
}

// --- GEMM: Mout[M,128](bf16) = dinv[r] * (A[M,128] @ W[128,128]) ------------
__global__ __launch_bounds__(128) void gemm_128(const void* __restrict__ Ain, int a_bf16,
                                                const float* __restrict__ W,
                                                const float* __restrict__ dinv,
                                                unsigned short* __restrict__ Mout, int M) {
    __shared__ float As[64 * 129];
    const int t = threadIdx.x;
    const int row0 = blockIdx.x * 64;
    if (a_bf16) {
        const uint4* A4 = (const uint4*)Ain;
        for (int i = t; i < 64 * 16; i += 128) {
            int r = i >> 4, c8 = i & 15;
            int gr = row0 + r;
            uint4 v = make_uint4(0u, 0u, 0u, 0u);
            if (gr < M) v = A4[(size_t)gr * 16 + c8];
            float* dst = &As[r * 129 + c8 * 8];
            unsigned u[4] = {v.x, v.y, v.z, v.w};
#pragma unroll
            for (int q = 0; q < 4; q++) {
                dst[2 * q]     = bf_lo(u[q]);
                dst[2 * q + 1] = bf_hi(u[q]);
            }
        }
    } else {
        const float4* A4 = (const float4*)Ain;
        for (int i = t; i < 64 * 32; i += 128) {
            int r = i >> 5, c4 = i & 31;
            int gr = row0 + r;
            float4 v = make_float4(0.f, 0.f, 0.f, 0.f);
            if (gr < M) v = A4[(size_t)gr * 32 + c4];
            float* dst = &As[r * 129 + c4 * 4];
            dst[0] = v.x; dst[1] = v.y; dst[2] = v.z; dst[3] = v.w;
        }
    }
    __syncthreads();
    const int tx = t & 15, ty = t >> 4;
    float acc[8][8];
#pragma unroll
    for (int i = 0; i < 8; i++)
#pragma unroll
        for (int j = 0; j < 8; j++) acc[i][j] = 0.f;
    const float* Ab = &As[(ty * 8) * 129];
    const float4* W4 = (const float4*)W;
#pragma unroll 2
    for (int k = 0; k < 128; k++) {
        float a[8];
#pragma unroll
        for (int i = 0; i < 8; i++) a[i] = Ab[i * 129 + k];
        float4 b0 = W4[k * 32 + tx * 2];
        float4 b1 = W4[k * 32 + tx * 2 + 1];
        float bb[8] = {b0.x, b0.y, b0.z, b0.w, b1.x, b1.y, b1.z, b1.w};
#pragma unroll
        for (int i = 0; i < 8; i++)
#pragma unroll
            for (int j = 0; j < 8; j++) acc[i][j] = fmaf(a[i], bb[j], acc[i][j]);
    }
#pragma unroll
    for (int i = 0; i < 8; i++) {
        int gr = row0 + ty * 8 + i;
        if (gr < M) {
            float dv = dinv[gr];
            unsigned p0 = bf16pair(acc[i][0] * dv, acc[i][1] * dv);
            unsigned p1 = bf16pair(acc[i][2] * dv, acc[i][3] * dv);
            unsigned p2 = bf16pair(acc[i][4] * dv, acc[i][5] * dv);
            unsigned p3 = bf16pair(acc[i][6] * dv, acc[i][7] * dv);
            *(uint4*)(Mout + (size_t)gr * 128 + tx * 8) = make_uint4(p0, p1, p2, p3);
        }
    }
}

// --- aggregation: out[v] = dinv[v]*sum_{e} m'[src_e] + b  (m' bf16, 256B/row)
__global__ __launch_bounds__(256) void agg_kernel(const unsigned* __restrict__ m,
                                                  const int* __restrict__ csr,
                                                  const int* __restrict__ row_off,
                                                  const unsigned* __restrict__ deg,
                                                  const float* __restrict__ dinv,
                                                  const float* __restrict__ bias,
                                                  void* __restrict__ outp, int n, int mode) {
    int wid = threadIdx.x >> 6, lane = threadIdx.x & 63;
    int v = blockIdx.x * 4 + wid;
    if (v >= n) return;
    int start = row_off[v];
    int cnt = (int)deg[v];
    float ax = 0.f, ay = 0.f;
    int e = 0;
    while (e < cnt) {
        int nload = cnt - e;
        if (nload > 64) nload = 64;
        int sv = 0;
        if (lane < nload) sv = csr[start + e + lane];
        int j = 0;
        for (; j + 16 <= nload; j += 16) {
            unsigned w[16];
#pragma unroll
            for (int q = 0; q < 16; q++) {
                int s = __shfl(sv, j + q);
                w[q] = m[(size_t)s * 64 + lane];
            }
#pragma unroll
            for (int q = 0; q < 16; q++) { ax += bf_lo(w[q]); ay += bf_hi(w[q]); }
        }
        if (j + 8 <= nload) {
            unsigned w[8];
#pragma unroll
            for (int q = 0; q < 8; q++) {
                int s = __shfl(sv, j + q);
                w[q] = m[(size_t)s * 64 + lane];
            }
#pragma unroll
            for (int q = 0; q < 8; q++) { ax += bf_lo(w[q]); ay += bf_hi(w[q]); }
            j += 8;
        }
        for (; j < nload; j++) {
            int s = __shfl(sv, j);
            unsigned w = m[(size_t)s * 64 + lane];
            ax += bf_lo(w); ay += bf_hi(w);
        }
        e += nload;
    }
    float dv = dinv[v];
    float2 b = ((const float2*)bias)[lane];
    float ox = fmaf(dv, ax, b.x), oy = fmaf(dv, ay, b.y);
    if (mode) {
        ox = fmaxf(ox, 0.f); oy = fmaxf(oy, 0.f);
        ((unsigned*)outp)[(size_t)v * 64 + lane] = bf16pair(ox, oy);
    } else {
        ((float2*)outp)[(size_t)v * 64 + lane] = make_float2(ox, oy);
    }
}

extern "C" void kernel_launch(void* const* d_in, const int* in_sizes, int n_in,
                              void* d_out, int out_size, void* d_ws, size_t ws_size,
                              hipStream_t stream) {
    const float*    x  = (const float*)d_in[0];
    const float*    W1 = (const float*)d_in[1];
    const float*    b1 = (const float*)d_in[2];
    const float*    W2 = (const float*)d_in[3];
    const float*    b2 = (const float*)d_in[4];
    const unsigned* ei = (const unsigned*)d_in[5];
    int n = in_sizes[0] / 128;
    int E = in_sizes[5] / 2;
    float* out = (float*)d_out;
    int NB = (n + RANGE - 1) >> RB;

    char* w = (char*)d_ws;
    size_t off = 0;
    auto alloc = [&](size_t bytes) -> void* {
        void* p = w + off;
        off = (off + bytes + 255) & ~(size_t)255;
        return p;
    };
    int*            flag     = (int*)alloc(4);
    unsigned*       deg      = (unsigned*)alloc((size_t)n * 4);
    float*          dinv     = (float*)alloc((size_t)n * 4);
    int*            row_off  = (int*)alloc((size_t)n * 4);
    unsigned*       partials = (unsigned*)alloc(4096 * 4);
    unsigned*       gcur     = (unsigned*)alloc(512 * 4);
    unsigned*       recs     = (unsigned*)alloc((size_t)NB * CAPB * 4);
    int*            csr      = (int*)alloc((size_t)(E + n) * 4);
    unsigned short* m_bf     = (unsigned short*)alloc((size_t)n * 128 * 2);
    unsigned*       h_bf     = (unsigned*)alloc((size_t)n * 64 * 4);
    (void)ws_size; (void)n_in; (void)out_size;

    int nb = (n + 1023) / 1024;
    int nchunk = (E + CHUNK - 1) / CHUNK;

    hipLaunchKernelGGL(detect_i64, dim3(1), dim3(256), 0, stream, ei, E, flag);
    hipLaunchKernelGGL(init_gcur, dim3((NB + 255) / 256), dim3(256), 0, stream, gcur, NB);
    hipLaunchKernelGGL(bucketA, dim3(nchunk), dim3(256), 0, stream, ei, E, n, flag, gcur, recs);
    hipLaunchKernelGGL(bucket_deg, dim3(NB), dim3(256), 0, stream, gcur, recs, deg, n);
    hipLaunchKernelGGL(dinv_kernel, dim3((n + 255) / 256), dim3(256), 0, stream, deg, dinv, n);
    hipLaunchKernelGGL(scan_block_sums, dim3(nb), dim3(256), 0, stream, deg, partials, n);
    hipLaunchKernelGGL(scan_partials, dim3(1), dim3(64), 0, stream, partials, nb);
    hipLaunchKernelGGL(scan_write, dim3(nb), dim3(256), 0, stream, deg, partials, row_off, n);
    hipLaunchKernelGGL(bucket_csr, dim3(NB), dim3(256), 0, stream, gcur, recs, row_off, csr, n);

    // layer 1: m = dinv*(x@W1) ; h = bf16(relu(agg(m) + b1))
    hipLaunchKernelGGL(gemm_128, dim3((n + 63) / 64), dim3(128), 0, stream,
                       (const void*)x, 0, W1, dinv, m_bf, n);
    hipLaunchKernelGGL(agg_kernel, dim3((n + 3) / 4), dim3(256), 0, stream,
                       (const unsigned*)m_bf, csr, row_off, deg, dinv, b1, (void*)h_bf, n, 1);
    // layer 2: m = dinv*(h@W2) ; out = agg(m) + b2
    hipLaunchKernelGGL(gemm_128, dim3((n + 63) / 64), dim3(128), 0, stream,
                       (const void*)h_bf, 1, W2, dinv, m_bf, n);
    hipLaunchKernelGGL(agg_kernel, dim3((n + 3) / 4), dim3(256), 0, stream,
                       (const unsigned*)m_bf, csr, row_off, deg, dinv, b2, (void*)out, n, 0);
}

// Round 4
// 262.043 us; speedup vs baseline: 2.9480x; 1.3182x over previous
//
#include <hip/hip_runtime.h>

// ---------------------------------------------------------------------------
// 2-layer GCN forward:  out = A_norm * relu(A_norm * (x@W1) + b1) @ W2 + b2
// A_norm = D^-1/2 (A+I) D^-1/2, applied as dinv[dst] * sum( dinv[src]*m[src] )
// m stored bf16 with dinv[src] pre-folded. CSR built via 512-node buckets.
// GEMMs run on MFMA with split-bf16 (hi+lo) for fp32-level accuracy.
// ---------------------------------------------------------------------------

#define RB    9
#define RANGE 512
#define CAPB  16384
#define CHUNK 8192

typedef __attribute__((ext_vector_type(8))) short bf16x8;
typedef __attribute__((ext_vector_type(4))) float f32x4;

__device__ inline float bf_lo(unsigned w) { return __uint_as_float(w << 16); }
__device__ inline float bf_hi(unsigned w) { return __uint_as_float(w & 0xffff0000u); }
__device__ inline unsigned bf16pair(float lo, float hi) {  // RNE pack
    unsigned a = __float_as_uint(lo), b = __float_as_uint(hi);
    a += 0x7fffu + ((a >> 16) & 1u);
    b += 0x7fffu + ((b >> 16) & 1u);
    return (a >> 16) | (b & 0xffff0000u);
}
__device__ inline unsigned short bf16rne(float f) {
    unsigned u = __float_as_uint(f);
    u += 0x7fffu + ((u >> 16) & 1u);
    return (unsigned short)(u >> 16);
}
__device__ inline float bf2f(unsigned short h) { return __uint_as_float(((unsigned)h) << 16); }

// --- edge_index dtype detection -------------------------------------------
__global__ void detect_i64(const unsigned* ei, int E, int* flag) {
    __shared__ int nz;
    if (threadIdx.x == 0) nz = 0;
    __syncthreads();
    int samples = E < 2048 ? E : 2048;
    int cnt = 0;
    for (int i = threadIdx.x; i < samples; i += blockDim.x)
        if (ei[2 * i + 1] != 0u) cnt++;
    if (cnt) atomicAdd(&nz, cnt);
    __syncthreads();
    if (threadIdx.x == 0) *flag = (nz == 0) ? 1 : 0;
}

__global__ void init_gcur(unsigned* gcur, int NB) {
    int b = blockIdx.x * blockDim.x + threadIdx.x;
    if (b < NB) gcur[b] = (unsigned)b * CAPB;
}

// --- phase A: edges -> per-bucket record arrays (4B records) ---------------
__global__ __launch_bounds__(256) void bucketA(const unsigned* __restrict__ ei, int E, int n,
                                               const int* __restrict__ flag,
                                               unsigned* __restrict__ gcur,
                                               unsigned* __restrict__ recs) {
    __shared__ unsigned hist[512];
    __shared__ unsigned offs[512];
    const int t = threadIdx.x;
    const int NB = (n + RANGE - 1) >> RB;
    for (int i = t; i < NB; i += 256) hist[i] = 0u;
    __syncthreads();
    const int base = blockIdx.x * CHUNK;
    const bool i64 = (*flag != 0);
    unsigned rec[32], bk[32];
#pragma unroll
    for (int j = 0; j < 32; j++) {
        int i = base + j * 256 + t;
        unsigned bv = 0xffffffffu, rv = 0u;
        if (i < E) {
            unsigned s, d;
            if (i64) { s = ei[2 * (size_t)i]; d = ei[2 * ((size_t)E + i)]; }
            else     { s = ei[i];             d = ei[(size_t)E + i]; }
            bv = d >> RB;
            rv = (s << RB) | (d & (RANGE - 1));
            atomicAdd(&hist[bv], 1u);
        }
        rec[j] = rv; bk[j] = bv;
    }
    __syncthreads();
    for (int b = t; b < NB; b += 256) {
        unsigned h = hist[b];
        offs[b] = h ? atomicAdd(&gcur[b], h) : 0u;
    }
    __syncthreads();
#pragma unroll
    for (int j = 0; j < 32; j++) {
        unsigned b = bk[j];
        if (b != 0xffffffffu) {
            unsigned pos = atomicAdd(&offs[b], 1u);
            if (pos < (b + 1u) * CAPB) recs[pos] = rec[j];
        }
    }
}

__global__ __launch_bounds__(256) void bucket_deg(const unsigned* __restrict__ gcur,
                                                  const unsigned* __restrict__ recs,
                                                  unsigned* __restrict__ deg, int n) {
    __shared__ unsigned dl[RANGE];
    const int b = blockIdx.x, t = threadIdx.x;
    const int node0 = b << RB;
    for (int v = t; v < RANGE; v += 256) dl[v] = 1u;
    __syncthreads();
    unsigned base = (unsigned)b * CAPB;
    unsigned cnt = gcur[b] - base; if (cnt > CAPB) cnt = CAPB;
    for (unsigned i = t; i < cnt; i += 256)
        atomicAdd(&dl[recs[base + i] & (RANGE - 1)], 1u);
    __syncthreads();
    for (int v = t; v < RANGE; v += 256)
        if (node0 + v < n) deg[node0 + v] = dl[v];
}

__global__ void dinv_kernel(const unsigned* deg, float* dinv, int n) {
    int i = blockIdx.x * blockDim.x + threadIdx.x;
    if (i < n) dinv[i] = rsqrtf((float)deg[i]);
}

// --- exclusive scan of deg -> row_off --------------------------------------
__global__ void scan_block_sums(const unsigned* deg, unsigned* partials, int n) {
    __shared__ unsigned sdata[256];
    int b = blockIdx.x, t = threadIdx.x;
    int base = b * 1024;
    unsigned s = 0;
    for (int j = 0; j < 4; j++) {
        int i = base + t * 4 + j;
        if (i < n) s += deg[i];
    }
    sdata[t] = s;
    __syncthreads();
    for (int stride = 128; stride > 0; stride >>= 1) {
        if (t < stride) sdata[t] += sdata[t + stride];
        __syncthreads();
    }
    if (t == 0) partials[b] = sdata[0];
}

__global__ void scan_partials(unsigned* partials, int nb) {
    if (threadIdx.x == 0 && blockIdx.x == 0) {
        unsigned run = 0;
        for (int i = 0; i < nb; i++) { unsigned v = partials[i]; partials[i] = run; run += v; }
    }
}

__global__ void scan_write(const unsigned* deg, const unsigned* partials,
                           int* row_off, int n) {
    int b = blockIdx.x, t = threadIdx.x;
    int lane = t & 63, wid = t >> 6;
    int base = b * 1024;
    unsigned vals[4];
    unsigned s = 0;
    for (int j = 0; j < 4; j++) {
        int i = base + t * 4 + j;
        vals[j] = (i < n) ? deg[i] : 0u;
        s += vals[j];
    }
    unsigned inc = s;
    for (int o = 1; o < 64; o <<= 1) {
        unsigned u = (unsigned)__shfl_up((int)inc, o, 64);
        if (lane >= o) inc += u;
    }
    __shared__ unsigned wtot[4];
    if (lane == 63) wtot[wid] = inc;
    __syncthreads();
    unsigned wbase = 0;
    for (int w = 0; w < wid; w++) wbase += wtot[w];
    unsigned excl = partials[b] + wbase + (inc - s);
    for (int j = 0; j < 4; j++) {
        int i = base + t * 4 + j;
        if (i < n) { row_off[i] = (int)excl; excl += vals[j]; }
    }
}

// --- phase B: per-bucket CSR scatter ---------------------------------------
__global__ __launch_bounds__(256) void bucket_csr(const unsigned* __restrict__ gcur,
                                                  const unsigned* __restrict__ recs,
                                                  const int* __restrict__ row_off,
                                                  int* __restrict__ csr, int n) {
    __shared__ int cur[RANGE];
    const int b = blockIdx.x, t = threadIdx.x;
    const int node0 = b << RB;
    for (int v = t; v < RANGE; v += 256) {
        int node = node0 + v;
        if (node < n) {
            int ro = row_off[node];
            csr[ro] = node;
            cur[v] = ro + 1;
        }
    }
    __syncthreads();
    unsigned base = (unsigned)b * CAPB;
    unsigned cnt = gcur[b] - base; if (cnt > CAPB) cnt = CAPB;
    for (unsigned i = t; i < cnt; i += 256) {
        unsigned r = recs[base + i];
        int pos = atomicAdd(&cur[r & (RANGE - 1)], 1);
        csr[pos] = (int)(r >> RB);
    }
}

// --- pack W[128,128] into MFMA B-fragment layout (hi/lo split) -------------
// Bpack[(nt*4+ks)*64 + lane] = 8 bf16: W[ks*32+(lane>>4)*8+b][nt*16+(lane&15)]
__global__ void pack_w(const float* __restrict__ W, uint4* __restrict__ Bhi,
                       uint4* __restrict__ Blo) {
    int idx = blockIdx.x * 256 + threadIdx.x;  // 0..2047
    int lane = idx & 63, ks = (idx >> 6) & 3, nt = idx >> 8;
    int j = nt * 16 + (lane & 15);
    int k0 = ks * 32 + ((lane >> 4) & 3) * 8;
    unsigned hi[4], lo[4];
#pragma unroll
    for (int p = 0; p < 4; p++) {
        float w0 = W[(size_t)(k0 + 2 * p) * 128 + j];
        float w1 = W[(size_t)(k0 + 2 * p + 1) * 128 + j];
        unsigned short h0 = bf16rne(w0), h1 = bf16rne(w1);
        unsigned short l0 = bf16rne(w0 - bf2f(h0)), l1 = bf16rne(w1 - bf2f(h1));
        hi[p] = (unsigned)h0 | ((unsigned)h1 << 16);
        lo[p] = (unsigned)l0 | ((unsigned)l1 << 16);
    }
    Bhi[idx] = make_uint4(hi[0], hi[1], hi[2], hi[3]);
    Blo[idx] = make_uint4(lo[0], lo[1], lo[2], lo[3]);
}

// --- MFMA GEMM: Mout[M,128](bf16) = dinv[r] * (A[M,128] @ W) ----------------
// SPLIT=1: A fp32, split hi/lo (3 mfma terms). SPLIT=0: A bf16 (2 mfma terms).
template <int SPLIT>
__global__ __launch_bounds__(256) void gemm_mfma(const void* __restrict__ Ain,
                                                 const uint4* __restrict__ Bhi,
                                                 const uint4* __restrict__ Blo,
                                                 const float* __restrict__ dinv,
                                                 unsigned short* __restrict__ Mout, int M) {
    __shared__ unsigned short Ahi[64 * 128];
    __shared__ unsigned short Alo[SPLIT ? 64 * 128 : 64];
    const int t = threadIdx.x;
    const int row0 = blockIdx.x * 64;
    char* ah8 = (char*)Ahi;
    char* al8 = (char*)Alo;

    if (SPLIT) {
        const float4* A4 = (const float4*)Ain;
#pragma unroll
        for (int it = 0; it < 4; it++) {
            int i = it * 256 + t;
            int r = i >> 4, c8 = i & 15;
            int gr = row0 + r;
            float4 v0 = make_float4(0.f, 0.f, 0.f, 0.f), v1 = v0;
            if (gr < M) { v0 = A4[(size_t)gr * 32 + c8 * 2]; v1 = A4[(size_t)gr * 32 + c8 * 2 + 1]; }
            float f[8] = {v0.x, v0.y, v0.z, v0.w, v1.x, v1.y, v1.z, v1.w};
            unsigned hp[4], lp[4];
#pragma unroll
            for (int p = 0; p < 4; p++) {
                unsigned short h0 = bf16rne(f[2 * p]), h1 = bf16rne(f[2 * p + 1]);
                unsigned short l0 = bf16rne(f[2 * p] - bf2f(h0));
                unsigned short l1 = bf16rne(f[2 * p + 1] - bf2f(h1));
                hp[p] = (unsigned)h0 | ((unsigned)h1 << 16);
                lp[p] = (unsigned)l0 | ((unsigned)l1 << 16);
            }
            int byte = (r * 256 + c8 * 16) ^ ((r & 7) << 4);
            *(uint4*)(ah8 + byte) = make_uint4(hp[0], hp[1], hp[2], hp[3]);
            *(uint4*)(al8 + byte) = make_uint4(lp[0], lp[1], lp[2], lp[3]);
        }
    } else {
        const uint4* A4 = (const uint4*)Ain;
#pragma unroll
        for (int it = 0; it < 4; it++) {
            int i = it * 256 + t;
            int r = i >> 4, c8 = i & 15;
            int gr = row0 + r;
            uint4 v = make_uint4(0u, 0u, 0u, 0u);
            if (gr < M) v = A4[(size_t)gr * 16 + c8];
            int byte = (r * 256 + c8 * 16) ^ ((r & 7) << 4);
            *(uint4*)(ah8 + byte) = v;
        }
    }
    __syncthreads();

    const int wv = t >> 6, lane = t & 63;
    const int arow = wv * 16 + (lane & 15);
    const int kh = ((lane >> 4) & 3) * 8;
    f32x4 acc[8];
#pragma unroll
    for (int nt = 0; nt < 8; nt++) acc[nt] = (f32x4){0.f, 0.f, 0.f, 0.f};
    float dv[4];
    const int orow0 = row0 + wv * 16 + ((lane >> 4) & 3) * 4;
#pragma unroll
    for (int r = 0; r < 4; r++) {
        int rr = orow0 + r;
        dv[r] = (rr < M) ? dinv[rr] : 0.f;
    }
#pragma unroll
    for (int ks = 0; ks < 4; ks++) {
        int byte = (arow * 256 + (ks * 32 + kh) * 2) ^ ((arow & 7) << 4);
        bf16x8 a_h = *(const bf16x8*)(ah8 + byte);
        bf16x8 a_l;
        if (SPLIT) a_l = *(const bf16x8*)(al8 + byte);
#pragma unroll
        for (int nt = 0; nt < 8; nt++) {
            uint4 bhv = Bhi[(nt * 4 + ks) * 64 + lane];
            uint4 blv = Blo[(nt * 4 + ks) * 64 + lane];
            bf16x8 bh = *(bf16x8*)&bhv;
            bf16x8 bl = *(bf16x8*)&blv;
            acc[nt] = __builtin_amdgcn_mfma_f32_16x16x32_bf16(a_h, bh, acc[nt], 0, 0, 0);
            if (SPLIT) acc[nt] = __builtin_amdgcn_mfma_f32_16x16x32_bf16(a_l, bh, acc[nt], 0, 0, 0);
            acc[nt] = __builtin_amdgcn_mfma_f32_16x16x32_bf16(a_h, bl, acc[nt], 0, 0, 0);
        }
    }
    __syncthreads();
    // epilogue: acc -> (bf16 * dinv) via LDS transpose -> coalesced stores
#pragma unroll
    for (int nt = 0; nt < 8; nt++) {
#pragma unroll
        for (int r = 0; r < 4; r++) {
            int lr = wv * 16 + ((lane >> 4) & 3) * 4 + r;
            int byte = (lr * 256 + (nt * 16 + (lane & 15)) * 2) ^ ((lr & 7) << 4);
            *(unsigned short*)(ah8 + byte) = bf16rne(acc[nt][r] * dv[r]);
        }
    }
    __syncthreads();
#pragma unroll
    for (int it = 0; it < 4; it++) {
        int i = it * 256 + t;
        int r = i >> 4, c8 = i & 15;
        int gr = row0 + r;
        if (gr < M) {
            int byte = (r * 256 + c8 * 16) ^ ((r & 7) << 4);
            *(uint4*)(Mout + (size_t)gr * 128 + c8 * 8) = *(uint4*)(ah8 + byte);
        }
    }
}

// --- aggregation: out[v] = dinv[v]*sum_{e} m'[src_e] + b  (m' bf16) --------
__global__ __launch_bounds__(256) void agg_kernel(const unsigned* __restrict__ m,
                                                  const int* __restrict__ csr,
                                                  const int* __restrict__ row_off,
                                                  const unsigned* __restrict__ deg,
                                                  const float* __restrict__ dinv,
                                                  const float* __restrict__ bias,
                                                  void* __restrict__ outp, int n, int mode) {
    int wid = threadIdx.x >> 6, lane = threadIdx.x & 63;
    int v = blockIdx.x * 4 + wid;
    if (v >= n) return;
    int start = row_off[v];
    int cnt = (int)deg[v];
    float ax = 0.f, ay = 0.f;
    int e = 0;
    while (e < cnt) {
        int nload = cnt - e;
        if (nload > 64) nload = 64;
        int sv = 0;
        if (lane < nload) sv = csr[start + e + lane];
        int j = 0;
        for (; j + 16 <= nload; j += 16) {
            unsigned w[16];
#pragma unroll
            for (int q = 0; q < 16; q++) {
                int s = __shfl(sv, j + q);
                w[q] = m[(size_t)s * 64 + lane];
            }
#pragma unroll
            for (int q = 0; q < 16; q++) { ax += bf_lo(w[q]); ay += bf_hi(w[q]); }
        }
        if (j + 8 <= nload) {
            unsigned w[8];
#pragma unroll
            for (int q = 0; q < 8; q++) {
                int s = __shfl(sv, j + q);
                w[q] = m[(size_t)s * 64 + lane];
            }
#pragma unroll
            for (int q = 0; q < 8; q++) { ax += bf_lo(w[q]); ay += bf_hi(w[q]); }
            j += 8;
        }
        for (; j < nload; j++) {
            int s = __shfl(sv, j);
            unsigned w = m[(size_t)s * 64 + lane];
            ax += bf_lo(w); ay += bf_hi(w);
        }
        e += nload;
    }
    float dv = dinv[v];
    float2 b = ((const float2*)bias)[lane];
    float ox = fmaf(dv, ax, b.x), oy = fmaf(dv, ay, b.y);
    if (mode) {
        ox = fmaxf(ox, 0.f); oy = fmaxf(oy, 0.f);
        ((unsigned*)outp)[(size_t)v * 64 + lane] = bf16pair(ox, oy);
    } else {
        ((float2*)outp)[(size_t)v * 64 + lane] = make_float2(ox, oy);
    }
}

extern "C" void kernel_launch(void* const* d_in, const int* in_sizes, int n_in,
                              void* d_out, int out_size, void* d_ws, size_t ws_size,
                              hipStream_t stream) {
    const float*    x  = (const float*)d_in[0];
    const float*    W1 = (const float*)d_in[1];
    const float*    b1 = (const float*)d_in[2];
    const float*    W2 = (const float*)d_in[3];
    const float*    b2 = (const float*)d_in[4];
    const unsigned* ei = (const unsigned*)d_in[5];
    int n = in_sizes[0] / 128;
    int E = in_sizes[5] / 2;
    float* out = (float*)d_out;
    int NB = (n + RANGE - 1) >> RB;

    char* w = (char*)d_ws;
    size_t off = 0;
    auto alloc = [&](size_t bytes) -> void* {
        void* p = w + off;
        off = (off + bytes + 255) & ~(size_t)255;
        return p;
    };
    int*            flag     = (int*)alloc(4);
    unsigned*       deg      = (unsigned*)alloc((size_t)n * 4);
    float*          dinv     = (float*)alloc((size_t)n * 4);
    int*            row_off  = (int*)alloc((size_t)n * 4);
    unsigned*       partials = (unsigned*)alloc(4096 * 4);
    unsigned*       gcur     = (unsigned*)alloc(512 * 4);
    uint4*          Bhi1     = (uint4*)alloc(2048 * 16);
    uint4*          Blo1     = (uint4*)alloc(2048 * 16);
    uint4*          Bhi2     = (uint4*)alloc(2048 * 16);
    uint4*          Blo2     = (uint4*)alloc(2048 * 16);
    unsigned*       recs     = (unsigned*)alloc((size_t)NB * CAPB * 4);
    int*            csr      = (int*)alloc((size_t)(E + n) * 4);
    unsigned short* m_bf     = (unsigned short*)alloc((size_t)n * 128 * 2);
    unsigned*       h_bf     = (unsigned*)alloc((size_t)n * 64 * 4);
    (void)ws_size; (void)n_in; (void)out_size;

    int nb = (n + 1023) / 1024;
    int nchunk = (E + CHUNK - 1) / CHUNK;

    hipLaunchKernelGGL(detect_i64, dim3(1), dim3(256), 0, stream, ei, E, flag);
    hipLaunchKernelGGL(init_gcur, dim3((NB + 255) / 256), dim3(256), 0, stream, gcur, NB);
    hipLaunchKernelGGL(pack_w, dim3(8), dim3(256), 0, stream, W1, Bhi1, Blo1);
    hipLaunchKernelGGL(pack_w, dim3(8), dim3(256), 0, stream, W2, Bhi2, Blo2);
    hipLaunchKernelGGL(bucketA, dim3(nchunk), dim3(256), 0, stream, ei, E, n, flag, gcur, recs);
    hipLaunchKernelGGL(bucket_deg, dim3(NB), dim3(256), 0, stream, gcur, recs, deg, n);
    hipLaunchKernelGGL(dinv_kernel, dim3((n + 255) / 256), dim3(256), 0, stream, deg, dinv, n);
    hipLaunchKernelGGL(scan_block_sums, dim3(nb), dim3(256), 0, stream, deg, partials, n);
    hipLaunchKernelGGL(scan_partials, dim3(1), dim3(64), 0, stream, partials, nb);
    hipLaunchKernelGGL(scan_write, dim3(nb), dim3(256), 0, stream, deg, partials, row_off, n);
    hipLaunchKernelGGL(bucket_csr, dim3(NB), dim3(256), 0, stream, gcur, recs, row_off, csr, n);

    int gblocks = (n + 63) / 64;
    // layer 1: m = dinv*(x@W1) ; h = bf16(relu(agg(m) + b1))
    hipLaunchKernelGGL((gemm_mfma<1>), dim3(gblocks), dim3(256), 0, stream,
                       (const void*)x, Bhi1, Blo1, dinv, m_bf, n);
    hipLaunchKernelGGL(agg_kernel, dim3((n + 3) / 4), dim3(256), 0, stream,
                       (const unsigned*)m_bf, csr, row_off, deg, dinv, b1, (void*)h_bf, n, 1);
    // layer 2: m = dinv*(h@W2) ; out = agg(m) + b2
    hipLaunchKernelGGL((gemm_mfma<0>), dim3(gblocks), dim3(256), 0, stream,
                       (const void*)h_bf, Bhi2, Blo2, dinv, m_bf, n);
    hipLaunchKernelGGL(agg_kernel, dim3((n + 3) / 4), dim3(256), 0, stream,
                       (const unsigned*)m_bf, csr, row_off, deg, dinv, b2, (void*)out, n, 0);
}